// Round 1
// baseline (137.011 us; speedup 1.0000x reference)
//
#include <hip/hip_runtime.h>

#define BATCH 16
#define HH 512
#define WW 512
#define RSLICE 16
#define NSLICE (HH / RSLICE)   // 32

static constexpr size_t PLANE = (size_t)HH * WW;
static constexpr size_t COLP_ELEMS = (size_t)BATCH * NSLICE * WW; // 262144 floats (1 MB)
static constexpr size_t ROWS_ELEMS = (size_t)BATCH * HH;          // 8192 floats (32 KB)

// Kernel A: one block = (batch b, 16-row slice). Threads own 2 columns each
// (float2 loads). Computes luminance, horizontal/vertical excess-edge energy,
// accumulates per-column partial sums (deterministic, no atomics) and per-row
// sums (wave shfl reduce). No per-row barriers: the horizontal neighbor at
// wave boundaries is handled by redundant scalar loads on 3 lanes/block.
__global__ __launch_bounds__(256) void jbd_reduce(const float* __restrict__ ref,
                                                  const float* __restrict__ tgt,
                                                  float* __restrict__ colp,
                                                  float* __restrict__ rows) {
  const int t = threadIdx.x;          // 0..255, owns cols 2t, 2t+1
  const int lane = t & 63;
  const int wid = t >> 6;
  const bool bnd = (lane == 63) && (t != 255);  // needs next wave's first col
  const int slice = blockIdx.x & (NSLICE - 1);
  const int b = blockIdx.x >> 5;      // / NSLICE
  const int r0 = slice * RSLICE;
  const float* rb = ref + (size_t)b * 3 * PLANE;
  const float* tb = tgt + (size_t)b * 3 * PLANE;
  __shared__ float rowpart[RSLICE][4];

  float ca0 = 0.f, ca1 = 0.f;                    // per-column de_h accumulators
  float pLr0 = 0.f, pLr1 = 0.f, pLt0 = 0.f, pLt1 = 0.f; // prev-row luminances

  float2 A0, A1, A2, C0, C1, C2;                 // current row: ref/tgt x 3ch
  float br0 = 0.f, br1 = 0.f, br2 = 0.f, bt0 = 0.f, bt1 = 0.f, bt2 = 0.f;
  {
    const size_t o = (size_t)r0 * WW + 2 * t;
    A0 = *(const float2*)(rb + o);
    A1 = *(const float2*)(rb + o + PLANE);
    A2 = *(const float2*)(rb + o + 2 * PLANE);
    C0 = *(const float2*)(tb + o);
    C1 = *(const float2*)(tb + o + PLANE);
    C2 = *(const float2*)(tb + o + 2 * PLANE);
    if (bnd) {
      const size_t ob = o + 2;
      br0 = rb[ob]; br1 = rb[ob + PLANE]; br2 = rb[ob + 2 * PLANE];
      bt0 = tb[ob]; bt1 = tb[ob + PLANE]; bt2 = tb[ob + 2 * PLANE];
    }
  }
  float2 N0 = A0, N1 = A1, N2 = A2, M0 = C0, M1 = C1, M2 = C2;
  float nbr0 = 0.f, nbr1 = 0.f, nbr2 = 0.f, nbt0 = 0.f, nbt1 = 0.f, nbt2 = 0.f;

#pragma unroll 1
  for (int i = 0; i <= RSLICE; ++i) {
    const int h = r0 + i;
    const bool valid = (h < HH);      // block-uniform
    const float lr0 = 0.299f * A0.x + 0.587f * A1.x + 0.114f * A2.x;
    const float lr1 = 0.299f * A0.y + 0.587f * A1.y + 0.114f * A2.y;
    const float lt0 = 0.299f * C0.x + 0.587f * C1.x + 0.114f * C2.x;
    const float lt1 = 0.299f * C0.y + 0.587f * C1.y + 0.114f * C2.y;
    float blr = 0.f, blt = 0.f;
    if (bnd) {
      blr = 0.299f * br0 + 0.587f * br1 + 0.114f * br2;
      blt = 0.299f * bt0 + 0.587f * bt1 + 0.114f * bt2;
    }
    // prefetch next row (issued before this row's compute -> latency hidden)
    if (i < RSLICE && (h + 1) < HH) {
      const size_t o = (size_t)(h + 1) * WW + 2 * t;
      N0 = *(const float2*)(rb + o);
      N1 = *(const float2*)(rb + o + PLANE);
      N2 = *(const float2*)(rb + o + 2 * PLANE);
      M0 = *(const float2*)(tb + o);
      M1 = *(const float2*)(tb + o + PLANE);
      M2 = *(const float2*)(tb + o + 2 * PLANE);
      if (bnd) {
        const size_t ob = o + 2;
        nbr0 = rb[ob]; nbr1 = rb[ob + PLANE]; nbr2 = rb[ob + 2 * PLANE];
        nbt0 = tb[ob]; nbt1 = tb[ob + PLANE]; nbt2 = tb[ob + 2 * PLANE];
      }
    }
    // horizontal neighbor luminance (col 2t+2): shfl from lane+1, boundary override
    float nlr = __shfl_down(lr0, 1);
    float nlt = __shfl_down(lt0, 1);
    if (bnd) { nlr = blr; nlt = blt; }
    if (i < RSLICE) {  // de_h for this block's own rows
      ca0 += fmaxf(fabsf(lt0 - lt1) - fabsf(lr0 - lr1), 0.f);
      if (t < 255)  // de_h(511) does not exist
        ca1 += fmaxf(fabsf(lt1 - nlt) - fabsf(lr1 - nlr), 0.f);
    }
    if (i >= 1 && valid) {  // de_v for row h-1
      float dv = fmaxf(fabsf(lt0 - pLt0) - fabsf(lr0 - pLr0), 0.f)
               + fmaxf(fabsf(lt1 - pLt1) - fabsf(lr1 - pLr1), 0.f);
      dv += __shfl_xor(dv, 1);
      dv += __shfl_xor(dv, 2);
      dv += __shfl_xor(dv, 4);
      dv += __shfl_xor(dv, 8);
      dv += __shfl_xor(dv, 16);
      dv += __shfl_xor(dv, 32);
      if (lane == 0) rowpart[i - 1][wid] = dv;
    }
    pLr0 = lr0; pLr1 = lr1; pLt0 = lt0; pLt1 = lt1;
    A0 = N0; A1 = N1; A2 = N2; C0 = M0; C1 = M1; C2 = M2;
    br0 = nbr0; br1 = nbr1; br2 = nbr2; bt0 = nbt0; bt1 = nbt1; bt2 = nbt2;
  }
  __syncthreads();
  if (t < RSLICE) {
    const int h = r0 + t;
    if (h < HH - 1)  // de_v rows are 0..510
      rows[(size_t)b * HH + h] =
          rowpart[t][0] + rowpart[t][1] + rowpart[t][2] + rowpart[t][3];
  }
  *(float2*)&colp[((size_t)b * NSLICE + slice) * WW + 2 * t] = make_float2(ca0, ca1);
}

// Kernel B: per (direction, batch) phase statistics. idx = t + 64k all share
// phase t%8 (64 % 8 == 0), so each lane accumulates a single phase partial.
__global__ __launch_bounds__(64) void jbd_phase(const float* __restrict__ colp,
                                                const float* __restrict__ rows,
                                                int* __restrict__ results) {
  const int dir = blockIdx.x & 1;   // 0 = columns (de_h), 1 = rows (de_v)
  const int b = blockIdx.x >> 1;
  const int t = threadIdx.x;        // 0..63
  float s = 0.f;
  if (dir == 0) {
    for (int idx = t; idx < WW - 1; idx += 64) {
      float v = 0.f;
      for (int sl = 0; sl < NSLICE; ++sl)
        v += colp[((size_t)b * NSLICE + sl) * WW + idx];
      s += v;
    }
  } else {
    for (int idx = t; idx < HH - 1; idx += 64)
      s += rows[(size_t)b * HH + idx];
  }
  s *= (1.0f / 512.0f);  // line mean (reference divides by H resp. W = 512)
  // sum over lanes with equal t%8 -> per-phase sums S[t&7] in every lane
  float ps = s;
  ps += __shfl_xor(ps, 8);
  ps += __shfl_xor(ps, 16);
  ps += __shfl_xor(ps, 32);
  float tot = ps;
  tot += __shfl_xor(tot, 1);
  tot += __shfl_xor(tot, 2);
  tot += __shfl_xor(tot, 4);
  const int p = t & 7;
  const float cnt = (p == 7) ? 63.f : 64.f;   // 511 lines: phases 0..6 -> 64, 7 -> 63
  const float a_k = ps / cnt;
  const float bg = (tot - ps) / (511.f - cnt);
  float ratio = a_k / (bg + 1e-8f);
  int bk = p;
  // butterfly argmax over the 8 phases, ties -> smallest index (jnp.argmax)
  for (int m = 4; m >= 1; m >>= 1) {
    const float ro = __shfl_xor(ratio, m);
    const int ko = __shfl_xor(bk, m);
    if (ro > ratio || (ro == ratio && ko < bk)) { ratio = ro; bk = ko; }
  }
  if (t == 0) {
    const float thr = (float)(1.0 / 0.35);
    results[4 * b + 2 * dir] = bk;
    results[4 * b + 2 * dir + 1] = (ratio > thr) ? 1 : 0;
  }
}

// Kernel C: broadcast per-batch decisions to the (B,1,H,W) mask, float4 stores.
__global__ __launch_bounds__(256) void jbd_write(const int* __restrict__ results,
                                                 float* __restrict__ out) {
  const int idx = blockIdx.x * 256 + threadIdx.x;  // float4 index
  const int b = idx >> 16;          // 512*128 float4 per batch
  const int rem = idx & 65535;
  const int h = rem >> 7;
  const int wq = rem & 127;
  const int4 rs = ((const int4*)results)[b];  // {bk_h, blocked_h, bk_v, blocked_v}
  const bool rowm = (rs.w != 0) && ((h & 7) == rs.z) && (h < HH - 1);
  float4 o;
  float* po = (float*)&o;
  const int w0 = wq << 2;
#pragma unroll
  for (int j = 0; j < 4; ++j) {
    const int w = w0 + j;
    const bool colm = (rs.y != 0) && ((w & 7) == rs.x) && (w < WW - 1);
    po[j] = (rowm || colm) ? 1.0f : 0.0f;
  }
  ((float4*)out)[idx] = o;
}

extern "C" void kernel_launch(void* const* d_in, const int* in_sizes, int n_in,
                              void* d_out, int out_size, void* d_ws, size_t ws_size,
                              hipStream_t stream) {
  (void)in_sizes; (void)n_in; (void)out_size; (void)ws_size;
  const float* ref = (const float*)d_in[0];
  const float* tgt = (const float*)d_in[1];
  float* colp = (float*)d_ws;                 // [B][NSLICE][W]
  float* rows = colp + COLP_ELEMS;            // [B][H] (index 511 unused)
  int* results = (int*)(rows + ROWS_ELEMS);   // [B][4]
  jbd_reduce<<<BATCH * NSLICE, 256, 0, stream>>>(ref, tgt, colp, rows);
  jbd_phase<<<2 * BATCH, 64, 0, stream>>>(colp, rows, results);
  jbd_write<<<(BATCH * HH * WW / 4) / 256, 256, 0, stream>>>(results, (float*)d_out);
}